// Round 4
// baseline (343.110 us; speedup 1.0000x reference)
//
#include <hip/hip_runtime.h>
#include <hip/hip_bf16.h>
#include <utility>

// fUpModule CG tensor product, MAXL=5, TAUS=OUT_TAUS=8, BATCH=1024, fp32 I/O.
// R8: stage-1/stage-2 code is EXACTLY R4's verified-clean form (rolled
// runtime stage-2 loop, loads in-loop, inline FMA bodies). Two deltas:
//   (a) std folded into the stage-1 mid write (w_init deleted; numerics
//       validated in R6: absmax 0.03125 passed) -- single dispatch;
//   (b) 2x concurrency: each batch row is split across TWO blocks by
//       l-group (A = {0,1,2,5} ~1904 FMA/lane stage-2, B = {3,4} ~1792);
//       mid shrinks 4224 -> 2112 slots so LDS = 19.2 KB/block -> 8
//       blocks/CU (launch_bounds(256,8)), grid 2048, 32 waves/CU.
//       Chunks per block stay at 9, so barriers/block are unchanged.
// R6/R7 lesson: any restructuring of stage-2 weight loads (arrays or
// scalars carried across static_for lambda instantiations) -> SROA
// failure -> 70-160 MB scratch traffic. Do not touch stage-2 scheduling.

constexpr int NTRIP = 69;
constexpr int NL    = 6;
constexpr int BATCH = 1024;
constexpr int ROW   = 288;     // complex elements per activation/output row
constexpr int MID_LDS = 2112;  // float2 slots for mid buffer (19.2 KB block)

struct Meta {
    int tl1[NTRIP], tl2[NTRIP], tll[NTRIP];
    int tf1[NTRIP], tf2[NTRIP];   // complex offsets of F[l1], F[l2] blocks
    int ttloc[NTRIP];             // T start of this triple within its l group
    int trip_of_l[NL][16];
    int ntrips[NL];
    int mid_tau[NL], std_off[NL], w_off[NL], f_l[NL];
    int nch[NL];
    int ch_start[NL][8], ch_cnt[NL][8];
    int wave_of[NL][16];
};

constexpr Meta build_meta() {
    Meta m{};
    int fl[NL] = {};
    {
        int acc = 0;
        for (int l = 0; l < NL; l++) { fl[l] = acc; m.f_l[l] = acc; acc += 8 * (2 * l + 1); }
    }
    int idx = 0;
    for (int l1 = 0; l1 <= 5; l1++)
        for (int l2 = 0; l2 <= l1; l2++) {
            int lmax = (l1 + l2 < 5) ? (l1 + l2) : 5;
            for (int l = l1 - l2; l <= lmax; l++) {
                m.tl1[idx] = l1; m.tl2[idx] = l2; m.tll[idx] = l;
                m.tf1[idx] = fl[l1]; m.tf2[idx] = fl[l2];
                m.ttloc[idx] = 64 * m.ntrips[l];
                m.trip_of_l[l][m.ntrips[l]] = idx;
                m.ntrips[l]++;
                idx++;
            }
        }
    int so = 0, wo = 0;
    for (int l = 0; l < NL; l++) {
        m.mid_tau[l] = 64 * m.ntrips[l];
        m.std_off[l] = so; so += m.mid_tau[l];
        m.w_off[l]   = wo; wo += 8 * m.mid_tau[l];
    }
    // chunking (balanced) + greedy cost-balanced slot->wave assignment
    for (int l = 0; l < NL; l++) {
        const int TW = 2 * l + 1;
        const int maxslot = MID_LDS / (64 * TW);
        const int ntl = m.ntrips[l];
        const int nch = (ntl + maxslot - 1) / maxslot;
        m.nch[l] = nch;
        int done = 0;
        for (int c = 0; c < nch; c++) {
            int cnt = (ntl - done + (nch - c) - 1) / (nch - c);
            m.ch_start[l][c] = done; m.ch_cnt[l][c] = cnt; done += cnt;
        }
        for (int c = 0; c < nch; c++) {
            const int s0 = m.ch_start[l][c], cnt = m.ch_cnt[l][c];
            int cost[16] = {}; bool asg[16] = {};
            for (int i = 0; i < cnt; i++) {
                int trip = m.trip_of_l[l][s0 + i];
                int l1 = m.tl1[trip], l2 = m.tl2[trip];
                int tc = 0;
                for (int mi = 0; mi < TW; mi++) {
                    int base = mi - l;
                    int lo = base + l1 - l2; if (lo < 0) lo = 0;
                    int hi = base + l1 + l2; if (hi > 2 * l1) hi = 2 * l1;
                    tc += hi - lo + 1;
                }
                cost[i] = tc * 6 + (2 * l1 + 1 + 2 * l2 + 1) * 2;
            }
            int load[4] = {};
            for (int k = 0; k < cnt; k++) {
                int best = -1, bc = -1;
                for (int i = 0; i < cnt; i++)
                    if (!asg[i] && cost[i] > bc) { bc = cost[i]; best = i; }
                asg[best] = true;
                int wsel = 0;
                for (int w2 = 1; w2 < 4; w2++) if (load[w2] < load[wsel]) wsel = w2;
                m.wave_of[l][s0 + best] = wsel;
                load[wsel] += bc;
            }
        }
    }
    return m;
}

constexpr Meta MT = build_meta();
constexpr int WLEN = 35328;  // complex weights
static_assert(MT.w_off[5] + 8 * MT.mid_tau[5] == WLEN, "wlen");
static_assert(MT.std_off[5] + MT.mid_tau[5] == 4416, "stdlen");
// 9 chunks per block in each group
static_assert(MT.nch[0] + MT.nch[1] + MT.nch[2] + MT.nch[5] == 9, "grpA");
static_assert(MT.nch[3] + MT.nch[4] == 9, "grpB");

// ---------------------------------------------------- constexpr CG coeffs ---
constexpr double cfact(int n) {
    double r = 1.0;
    for (int i = 2; i <= n; i++) r *= (double)i;
    return r;
}
constexpr double csqrt(double x) {
    double g = x > 1.0 ? x : 1.0;
    for (int i = 0; i < 100; i++) g = 0.5 * (g + x / g);
    return g;
}
constexpr float cg_coeff(int l1, int l2, int l, int m1, int m2, int m) {
    if (m1 + m2 != m) return 0.0f;
    double pre = csqrt((double)(2 * l + 1) * cfact(l + l1 - l2) * cfact(l - l1 + l2) *
                       cfact(l1 + l2 - l) / cfact(l1 + l2 + l + 1));
    pre *= csqrt(cfact(l + m) * cfact(l - m) * cfact(l1 - m1) * cfact(l1 + m1) *
                 cfact(l2 - m2) * cfact(l2 + m2));
    double s = 0.0;
    for (int k = 0; k <= l1 + l2 - l; k++) {
        int d0 = k, d1 = l1 + l2 - l - k, d2 = l1 - m1 - k;
        int d3 = l2 + m2 - k, d4 = l - l2 + m1 + k, d5 = l - l1 - m2 + k;
        if (d0 < 0 || d1 < 0 || d2 < 0 || d3 < 0 || d4 < 0 || d5 < 0) continue;
        double den = cfact(d0) * cfact(d1) * cfact(d2) * cfact(d3) * cfact(d4) * cfact(d5);
        s += ((k & 1) ? -1.0 : 1.0) / den;
    }
    return (float)(pre * s);
}

// compile-time for
template <int... Is, class F>
__device__ __forceinline__ void static_for_impl(std::integer_sequence<int, Is...>, F&& f) {
    (f(std::integral_constant<int, Is>{}), ...);
}
template <int N, class F>
__device__ __forceinline__ void static_for(F&& f) {
    static_for_impl(std::make_integer_sequence<int, N>{}, (F&&)f);
}

// ------------------------------------------------------------- main kernel --
template <int L>
__device__ __forceinline__ void process_l(int b, int tid,
                                          const float2* __restrict__ F,
                                          float2* __restrict__ mid,
                                          const float2* __restrict__ w,
                                          const float* __restrict__ stdv,
                                          float2* __restrict__ out) {
    constexpr int TW  = 2 * L + 1;
    constexpr int NCH = MT.nch[L];
    constexpr int NT  = MT.mid_tau[L];

    const int wid  = tid >> 6;     // wave 0..3
    const int lane = tid & 63;     // stage1: ts = (t,s); stage2: T-lane
    const int t = lane >> 3, s = lane & 7;

    float2 acc0[TW], acc1[TW];     // o = wid, o = wid + 4
#pragma unroll
    for (int i = 0; i < TW; i++) { acc0[i] = make_float2(0.f, 0.f); acc1[i] = make_float2(0.f, 0.f); }

    static_for<NCH>([&](auto CHc) {
        constexpr int CH  = decltype(CHc)::value;
        constexpr int S0  = MT.ch_start[L][CH];
        constexpr int CNT = MT.ch_cnt[L][CH];
        constexpr int CT  = CNT * 64;            // T extent of this chunk
        static_assert(CT * TW <= MID_LDS, "chunk fits");

        __syncthreads();   // previous consumers of `mid` done (covers F load too)

        // ---- stage 1: mid[m][T] for slots [S0, S0+CNT), scaled by 1/std --
        static_for<CNT>([&](auto SIc) {
            constexpr int SI   = S0 + decltype(SIc)::value;
            constexpr int TRIP = MT.trip_of_l[L][SI];
            constexpr int L1   = MT.tl1[TRIP];
            constexpr int L2v  = MT.tl2[TRIP];
            constexpr int N1   = 2 * L1 + 1, N2 = 2 * L2v + 1;
            if (MT.wave_of[L][SI] == wid) {
                const float inv = 1.0f /
                    (stdv[MT.std_off[L] + MT.ttloc[TRIP] + lane] + 1e-5f);
                const float2* F1 = F + MT.tf1[TRIP] + t * N1;
                const float2* F2 = F + MT.tf2[TRIP] + s * N2;
                float2 f1[N1], f2[N2];
#pragma unroll
                for (int i = 0; i < N1; i++) f1[i] = F1[i];
#pragma unroll
                for (int i = 0; i < N2; i++) f2[i] = F2[i];
                const int Tloc = (MT.ttloc[TRIP] - S0 * 64) + lane;
                static_for<TW>([&](auto MIc) {
                    constexpr int MI   = decltype(MIc)::value;
                    constexpr int BASE = MI - L;   // m
                    constexpr int LO_  = BASE + L1 - L2v;
                    constexpr int LO   = LO_ < 0 ? 0 : LO_;
                    constexpr int HI_  = BASE + L1 + L2v;
                    constexpr int HI   = HI_ > 2 * L1 ? 2 * L1 : HI_;
                    float re = 0.f, im = 0.f;
                    static_for<HI - LO + 1>([&](auto Kc) {
                        constexpr int AI = LO + decltype(Kc)::value;
                        constexpr int CI = BASE + L1 + L2v - AI;
                        constexpr float cv = cg_coeff(L1, L2v, L, AI - L1, CI - L2v, BASE);
                        if constexpr (cv != 0.0f) {
                            const float2 a = f1[AI], c2 = f2[CI];
                            re = fmaf(cv, fmaf(-a.y, c2.y, a.x * c2.x), re);
                            im = fmaf(cv, fmaf(a.y, c2.x, a.x * c2.y), im);
                        }
                    });
                    mid[MI * CT + Tloc] = make_float2(re * inv, im * inv);
                });
            }
        });
        __syncthreads();

        // ---- stage 2: acc[o,m] += sum_T W[o,T]*mid[m][T]; 2 o's, 2 T's --
        // R4-verified form: rolled runtime loop, loads in-loop, inline body.
        {
            const float2* W0 = w + MT.w_off[L] + wid * NT + S0 * 64;
            const float2* W1 = w + MT.w_off[L] + (wid + 4) * NT + S0 * 64;
            for (int T = lane * 2; T < CT; T += 128) {
                const float4 w0 = *reinterpret_cast<const float4*>(W0 + T);
                const float4 w1 = *reinterpret_cast<const float4*>(W1 + T);
#pragma unroll
                for (int mi = 0; mi < TW; mi++) {
                    const float4 mv = *reinterpret_cast<const float4*>(mid + mi * CT + T);
                    acc0[mi].x = fmaf(w0.x, mv.x, fmaf(-w0.y, mv.y,
                                  fmaf(w0.z, mv.z, fmaf(-w0.w, mv.w, acc0[mi].x))));
                    acc0[mi].y = fmaf(w0.x, mv.y, fmaf(w0.y, mv.x,
                                  fmaf(w0.z, mv.w, fmaf(w0.w, mv.z, acc0[mi].y))));
                    acc1[mi].x = fmaf(w1.x, mv.x, fmaf(-w1.y, mv.y,
                                  fmaf(w1.z, mv.z, fmaf(-w1.w, mv.w, acc1[mi].x))));
                    acc1[mi].y = fmaf(w1.x, mv.y, fmaf(w1.y, mv.x,
                                  fmaf(w1.z, mv.w, fmaf(w1.w, mv.z, acc1[mi].y))));
                }
            }
        }
    });

    // merge-reduce: lo half ends with sum for o=wid, hi half for o=wid+4
    const bool lo = (lane < 32);
    float2 red[TW];
#pragma unroll
    for (int mi = 0; mi < TW; mi++) {
        float gx = lo ? acc1[mi].x : acc0[mi].x;   // value to give away
        float gy = lo ? acc1[mi].y : acc0[mi].y;
        float rx = (lo ? acc0[mi].x : acc1[mi].x) + __shfl_xor(gx, 32, 64);
        float ry = (lo ? acc0[mi].y : acc1[mi].y) + __shfl_xor(gy, 32, 64);
#pragma unroll
        for (int off = 16; off >= 1; off >>= 1) {
            rx += __shfl_xor(rx, off, 64);
            ry += __shfl_xor(ry, off, 64);
        }
        red[mi] = make_float2(rx, ry);
    }
    if (lane == 0 || lane == 32) {
        const int o = wid + (lo ? 0 : 4);
        float2* orow = out + (size_t)b * ROW + MT.f_l[L] + o * TW;
#pragma unroll
        for (int mi = 0; mi < TW; mi++) orow[mi] = red[mi];
    }
}

__global__ __launch_bounds__(256, 8) void fup_main(const float2* __restrict__ act,
                                                   const float2* __restrict__ w,
                                                   const float* __restrict__ stdv,
                                                   float2* __restrict__ out) {
    __shared__ float2 F[ROW];
    __shared__ __align__(16) float2 mid[MID_LDS];
    const int bid = blockIdx.x;
    const int grp = bid & 1;          // 0: l={0,1,2,5}; 1: l={3,4}
    const int b   = bid >> 1;
    const int tid = threadIdx.x;
    const float2* arow = act + (size_t)b * ROW;
    for (int i = tid; i < ROW; i += 256) F[i] = arow[i];
    // sync happens at top of first chunk inside the first process_l
    if (grp == 0) {
        process_l<0>(b, tid, F, mid, w, stdv, out);
        process_l<1>(b, tid, F, mid, w, stdv, out);
        process_l<2>(b, tid, F, mid, w, stdv, out);
        process_l<5>(b, tid, F, mid, w, stdv, out);
    } else {
        process_l<3>(b, tid, F, mid, w, stdv, out);
        process_l<4>(b, tid, F, mid, w, stdv, out);
    }
}

// ----------------------------------------------------------------- launch ---
extern "C" void kernel_launch(void* const* d_in, const int* in_sizes, int n_in,
                              void* d_out, int out_size, void* d_ws, size_t ws_size,
                              hipStream_t stream) {
    const float2* act  = (const float2*)d_in[0];
    const float2* wts  = (const float2*)d_in[1];
    const float*  stdv = (const float*)d_in[2];
    float2* out = (float2*)d_out;
    (void)d_ws; (void)ws_size;

    hipLaunchKernelGGL(fup_main, dim3(2 * BATCH), dim3(256), 0, stream,
                       act, wts, stdv, out);
}

// Round 5
// 123.950 us; speedup vs baseline: 2.7681x; 2.7681x over previous
//
#include <hip/hip_runtime.h>
#include <hip/hip_bf16.h>
#include <utility>

// fUpModule CG tensor product, MAXL=5, TAUS=OUT_TAUS=8, BATCH=1024, fp32 I/O.
// R9: identical to R8 except __launch_bounds__(256, 4).
// R8 lesson: launch_bounds(256,8) CAPS the allocator at 2048/8 = 64 VGPR
// (it squeezed to 32) -> acc/f1/f2 spill -> 599 MB scratch. The l-split +
// 19.2 KB LDS were fine. With (256,4) (cap 128) this code compiles to
// 64 VGPR (R4-verified), and at 64 VGPR the HW schedules 8 blocks/CU on
// its own (LDS 19.4 KB also allows 8). Occupancy comes from the compiled
// register count, not from the launch-bounds demand.
//   (a) std folded into stage-1 mid write (validated R6; single dispatch);
//   (b) 2x concurrency: each batch row split across TWO blocks by l-group
//       (A = {0,1,2,5}, B = {3,4}); mid = 2112 slots; grid 2048;
//       9 chunks per block in both groups, so barriers/block unchanged.
// R6/R7 lesson: do not restructure stage-2 loads (SROA failure -> scratch).

constexpr int NTRIP = 69;
constexpr int NL    = 6;
constexpr int BATCH = 1024;
constexpr int ROW   = 288;     // complex elements per activation/output row
constexpr int MID_LDS = 2112;  // float2 slots for mid buffer (19.2 KB block)

struct Meta {
    int tl1[NTRIP], tl2[NTRIP], tll[NTRIP];
    int tf1[NTRIP], tf2[NTRIP];   // complex offsets of F[l1], F[l2] blocks
    int ttloc[NTRIP];             // T start of this triple within its l group
    int trip_of_l[NL][16];
    int ntrips[NL];
    int mid_tau[NL], std_off[NL], w_off[NL], f_l[NL];
    int nch[NL];
    int ch_start[NL][8], ch_cnt[NL][8];
    int wave_of[NL][16];
};

constexpr Meta build_meta() {
    Meta m{};
    int fl[NL] = {};
    {
        int acc = 0;
        for (int l = 0; l < NL; l++) { fl[l] = acc; m.f_l[l] = acc; acc += 8 * (2 * l + 1); }
    }
    int idx = 0;
    for (int l1 = 0; l1 <= 5; l1++)
        for (int l2 = 0; l2 <= l1; l2++) {
            int lmax = (l1 + l2 < 5) ? (l1 + l2) : 5;
            for (int l = l1 - l2; l <= lmax; l++) {
                m.tl1[idx] = l1; m.tl2[idx] = l2; m.tll[idx] = l;
                m.tf1[idx] = fl[l1]; m.tf2[idx] = fl[l2];
                m.ttloc[idx] = 64 * m.ntrips[l];
                m.trip_of_l[l][m.ntrips[l]] = idx;
                m.ntrips[l]++;
                idx++;
            }
        }
    int so = 0, wo = 0;
    for (int l = 0; l < NL; l++) {
        m.mid_tau[l] = 64 * m.ntrips[l];
        m.std_off[l] = so; so += m.mid_tau[l];
        m.w_off[l]   = wo; wo += 8 * m.mid_tau[l];
    }
    // chunking (balanced) + greedy cost-balanced slot->wave assignment
    for (int l = 0; l < NL; l++) {
        const int TW = 2 * l + 1;
        const int maxslot = MID_LDS / (64 * TW);
        const int ntl = m.ntrips[l];
        const int nch = (ntl + maxslot - 1) / maxslot;
        m.nch[l] = nch;
        int done = 0;
        for (int c = 0; c < nch; c++) {
            int cnt = (ntl - done + (nch - c) - 1) / (nch - c);
            m.ch_start[l][c] = done; m.ch_cnt[l][c] = cnt; done += cnt;
        }
        for (int c = 0; c < nch; c++) {
            const int s0 = m.ch_start[l][c], cnt = m.ch_cnt[l][c];
            int cost[16] = {}; bool asg[16] = {};
            for (int i = 0; i < cnt; i++) {
                int trip = m.trip_of_l[l][s0 + i];
                int l1 = m.tl1[trip], l2 = m.tl2[trip];
                int tc = 0;
                for (int mi = 0; mi < TW; mi++) {
                    int base = mi - l;
                    int lo = base + l1 - l2; if (lo < 0) lo = 0;
                    int hi = base + l1 + l2; if (hi > 2 * l1) hi = 2 * l1;
                    tc += hi - lo + 1;
                }
                cost[i] = tc * 6 + (2 * l1 + 1 + 2 * l2 + 1) * 2;
            }
            int load[4] = {};
            for (int k = 0; k < cnt; k++) {
                int best = -1, bc = -1;
                for (int i = 0; i < cnt; i++)
                    if (!asg[i] && cost[i] > bc) { bc = cost[i]; best = i; }
                asg[best] = true;
                int wsel = 0;
                for (int w2 = 1; w2 < 4; w2++) if (load[w2] < load[wsel]) wsel = w2;
                m.wave_of[l][s0 + best] = wsel;
                load[wsel] += bc;
            }
        }
    }
    return m;
}

constexpr Meta MT = build_meta();
constexpr int WLEN = 35328;  // complex weights
static_assert(MT.w_off[5] + 8 * MT.mid_tau[5] == WLEN, "wlen");
static_assert(MT.std_off[5] + MT.mid_tau[5] == 4416, "stdlen");
// 9 chunks per block in each group
static_assert(MT.nch[0] + MT.nch[1] + MT.nch[2] + MT.nch[5] == 9, "grpA");
static_assert(MT.nch[3] + MT.nch[4] == 9, "grpB");

// ---------------------------------------------------- constexpr CG coeffs ---
constexpr double cfact(int n) {
    double r = 1.0;
    for (int i = 2; i <= n; i++) r *= (double)i;
    return r;
}
constexpr double csqrt(double x) {
    double g = x > 1.0 ? x : 1.0;
    for (int i = 0; i < 100; i++) g = 0.5 * (g + x / g);
    return g;
}
constexpr float cg_coeff(int l1, int l2, int l, int m1, int m2, int m) {
    if (m1 + m2 != m) return 0.0f;
    double pre = csqrt((double)(2 * l + 1) * cfact(l + l1 - l2) * cfact(l - l1 + l2) *
                       cfact(l1 + l2 - l) / cfact(l1 + l2 + l + 1));
    pre *= csqrt(cfact(l + m) * cfact(l - m) * cfact(l1 - m1) * cfact(l1 + m1) *
                 cfact(l2 - m2) * cfact(l2 + m2));
    double s = 0.0;
    for (int k = 0; k <= l1 + l2 - l; k++) {
        int d0 = k, d1 = l1 + l2 - l - k, d2 = l1 - m1 - k;
        int d3 = l2 + m2 - k, d4 = l - l2 + m1 + k, d5 = l - l1 - m2 + k;
        if (d0 < 0 || d1 < 0 || d2 < 0 || d3 < 0 || d4 < 0 || d5 < 0) continue;
        double den = cfact(d0) * cfact(d1) * cfact(d2) * cfact(d3) * cfact(d4) * cfact(d5);
        s += ((k & 1) ? -1.0 : 1.0) / den;
    }
    return (float)(pre * s);
}

// compile-time for
template <int... Is, class F>
__device__ __forceinline__ void static_for_impl(std::integer_sequence<int, Is...>, F&& f) {
    (f(std::integral_constant<int, Is>{}), ...);
}
template <int N, class F>
__device__ __forceinline__ void static_for(F&& f) {
    static_for_impl(std::make_integer_sequence<int, N>{}, (F&&)f);
}

// ------------------------------------------------------------- main kernel --
template <int L>
__device__ __forceinline__ void process_l(int b, int tid,
                                          const float2* __restrict__ F,
                                          float2* __restrict__ mid,
                                          const float2* __restrict__ w,
                                          const float* __restrict__ stdv,
                                          float2* __restrict__ out) {
    constexpr int TW  = 2 * L + 1;
    constexpr int NCH = MT.nch[L];
    constexpr int NT  = MT.mid_tau[L];

    const int wid  = tid >> 6;     // wave 0..3
    const int lane = tid & 63;     // stage1: ts = (t,s); stage2: T-lane
    const int t = lane >> 3, s = lane & 7;

    float2 acc0[TW], acc1[TW];     // o = wid, o = wid + 4
#pragma unroll
    for (int i = 0; i < TW; i++) { acc0[i] = make_float2(0.f, 0.f); acc1[i] = make_float2(0.f, 0.f); }

    static_for<NCH>([&](auto CHc) {
        constexpr int CH  = decltype(CHc)::value;
        constexpr int S0  = MT.ch_start[L][CH];
        constexpr int CNT = MT.ch_cnt[L][CH];
        constexpr int CT  = CNT * 64;            // T extent of this chunk
        static_assert(CT * TW <= MID_LDS, "chunk fits");

        __syncthreads();   // previous consumers of `mid` done (covers F load too)

        // ---- stage 1: mid[m][T] for slots [S0, S0+CNT), scaled by 1/std --
        static_for<CNT>([&](auto SIc) {
            constexpr int SI   = S0 + decltype(SIc)::value;
            constexpr int TRIP = MT.trip_of_l[L][SI];
            constexpr int L1   = MT.tl1[TRIP];
            constexpr int L2v  = MT.tl2[TRIP];
            constexpr int N1   = 2 * L1 + 1, N2 = 2 * L2v + 1;
            if (MT.wave_of[L][SI] == wid) {
                const float inv = 1.0f /
                    (stdv[MT.std_off[L] + MT.ttloc[TRIP] + lane] + 1e-5f);
                const float2* F1 = F + MT.tf1[TRIP] + t * N1;
                const float2* F2 = F + MT.tf2[TRIP] + s * N2;
                float2 f1[N1], f2[N2];
#pragma unroll
                for (int i = 0; i < N1; i++) f1[i] = F1[i];
#pragma unroll
                for (int i = 0; i < N2; i++) f2[i] = F2[i];
                const int Tloc = (MT.ttloc[TRIP] - S0 * 64) + lane;
                static_for<TW>([&](auto MIc) {
                    constexpr int MI   = decltype(MIc)::value;
                    constexpr int BASE = MI - L;   // m
                    constexpr int LO_  = BASE + L1 - L2v;
                    constexpr int LO   = LO_ < 0 ? 0 : LO_;
                    constexpr int HI_  = BASE + L1 + L2v;
                    constexpr int HI   = HI_ > 2 * L1 ? 2 * L1 : HI_;
                    float re = 0.f, im = 0.f;
                    static_for<HI - LO + 1>([&](auto Kc) {
                        constexpr int AI = LO + decltype(Kc)::value;
                        constexpr int CI = BASE + L1 + L2v - AI;
                        constexpr float cv = cg_coeff(L1, L2v, L, AI - L1, CI - L2v, BASE);
                        if constexpr (cv != 0.0f) {
                            const float2 a = f1[AI], c2 = f2[CI];
                            re = fmaf(cv, fmaf(-a.y, c2.y, a.x * c2.x), re);
                            im = fmaf(cv, fmaf(a.y, c2.x, a.x * c2.y), im);
                        }
                    });
                    mid[MI * CT + Tloc] = make_float2(re * inv, im * inv);
                });
            }
        });
        __syncthreads();

        // ---- stage 2: acc[o,m] += sum_T W[o,T]*mid[m][T]; 2 o's, 2 T's --
        // R4-verified form: rolled runtime loop, loads in-loop, inline body.
        {
            const float2* W0 = w + MT.w_off[L] + wid * NT + S0 * 64;
            const float2* W1 = w + MT.w_off[L] + (wid + 4) * NT + S0 * 64;
            for (int T = lane * 2; T < CT; T += 128) {
                const float4 w0 = *reinterpret_cast<const float4*>(W0 + T);
                const float4 w1 = *reinterpret_cast<const float4*>(W1 + T);
#pragma unroll
                for (int mi = 0; mi < TW; mi++) {
                    const float4 mv = *reinterpret_cast<const float4*>(mid + mi * CT + T);
                    acc0[mi].x = fmaf(w0.x, mv.x, fmaf(-w0.y, mv.y,
                                  fmaf(w0.z, mv.z, fmaf(-w0.w, mv.w, acc0[mi].x))));
                    acc0[mi].y = fmaf(w0.x, mv.y, fmaf(w0.y, mv.x,
                                  fmaf(w0.z, mv.w, fmaf(w0.w, mv.z, acc0[mi].y))));
                    acc1[mi].x = fmaf(w1.x, mv.x, fmaf(-w1.y, mv.y,
                                  fmaf(w1.z, mv.z, fmaf(-w1.w, mv.w, acc1[mi].x))));
                    acc1[mi].y = fmaf(w1.x, mv.y, fmaf(w1.y, mv.x,
                                  fmaf(w1.z, mv.w, fmaf(w1.w, mv.z, acc1[mi].y))));
                }
            }
        }
    });

    // merge-reduce: lo half ends with sum for o=wid, hi half for o=wid+4
    const bool lo = (lane < 32);
    float2 red[TW];
#pragma unroll
    for (int mi = 0; mi < TW; mi++) {
        float gx = lo ? acc1[mi].x : acc0[mi].x;   // value to give away
        float gy = lo ? acc1[mi].y : acc0[mi].y;
        float rx = (lo ? acc0[mi].x : acc1[mi].x) + __shfl_xor(gx, 32, 64);
        float ry = (lo ? acc0[mi].y : acc1[mi].y) + __shfl_xor(gy, 32, 64);
#pragma unroll
        for (int off = 16; off >= 1; off >>= 1) {
            rx += __shfl_xor(rx, off, 64);
            ry += __shfl_xor(ry, off, 64);
        }
        red[mi] = make_float2(rx, ry);
    }
    if (lane == 0 || lane == 32) {
        const int o = wid + (lo ? 0 : 4);
        float2* orow = out + (size_t)b * ROW + MT.f_l[L] + o * TW;
#pragma unroll
        for (int mi = 0; mi < TW; mi++) orow[mi] = red[mi];
    }
}

__global__ __launch_bounds__(256, 4) void fup_main(const float2* __restrict__ act,
                                                   const float2* __restrict__ w,
                                                   const float* __restrict__ stdv,
                                                   float2* __restrict__ out) {
    __shared__ float2 F[ROW];
    __shared__ __align__(16) float2 mid[MID_LDS];
    const int bid = blockIdx.x;
    const int grp = bid & 1;          // 0: l={0,1,2,5}; 1: l={3,4}
    const int b   = bid >> 1;
    const int tid = threadIdx.x;
    const float2* arow = act + (size_t)b * ROW;
    for (int i = tid; i < ROW; i += 256) F[i] = arow[i];
    // sync happens at top of first chunk inside the first process_l
    if (grp == 0) {
        process_l<0>(b, tid, F, mid, w, stdv, out);
        process_l<1>(b, tid, F, mid, w, stdv, out);
        process_l<2>(b, tid, F, mid, w, stdv, out);
        process_l<5>(b, tid, F, mid, w, stdv, out);
    } else {
        process_l<3>(b, tid, F, mid, w, stdv, out);
        process_l<4>(b, tid, F, mid, w, stdv, out);
    }
}

// ----------------------------------------------------------------- launch ---
extern "C" void kernel_launch(void* const* d_in, const int* in_sizes, int n_in,
                              void* d_out, int out_size, void* d_ws, size_t ws_size,
                              hipStream_t stream) {
    const float2* act  = (const float2*)d_in[0];
    const float2* wts  = (const float2*)d_in[1];
    const float*  stdv = (const float*)d_in[2];
    float2* out = (float2*)d_out;
    (void)d_ws; (void)ws_size;

    hipLaunchKernelGGL(fup_main, dim3(2 * BATCH), dim3(256), 0, stream,
                       act, wts, stdv, out);
}